// Round 5
// baseline (362.410 us; speedup 1.0000x reference)
//
#include <hip/hip_runtime.h>
#include <stdint.h>

typedef unsigned short ushort_t;
typedef short bf16x8 __attribute__((ext_vector_type(8)));
typedef float f32x4 __attribute__((ext_vector_type(4)));
typedef float f32x16 __attribute__((ext_vector_type(16)));
typedef unsigned int uint4v __attribute__((ext_vector_type(4)));

#define HW_ 16384

__device__ __forceinline__ float bf2f(ushort_t u){
  return __uint_as_float(((unsigned)u) << 16);
}
__device__ __forceinline__ ushort_t f2bf(float f){
  unsigned u = __float_as_uint(f);
  u += 0x7fffu + ((u >> 16) & 1u);
  return (ushort_t)(u >> 16);
}
#define MFMA __builtin_amdgcn_mfma_f32_32x32x16_bf16

// ---------------------------------------------------------------------------
// Wp layout (ushort elements):
//   [0      .. 36864)  : score hi A-frags,  mtg 0..1 = Ws rows 0..63
//   [36864  .. 110592) : gxy  hi A-frags,   mtg 0..3 = Wx0,Wx1,Wy0,Wy1
//   [110592 .. 184320) : gxy  lo A-frags,   same order
// Within a group: [mtg][ks 0..35][lane 0..63][j 0..7];
// co' = mtg*32 + (lane&31); tap = ks>>2; ci = (ks&3)*16 + (lane>>5)*8 + j.
// ---------------------------------------------------------------------------
__global__ __launch_bounds__(256) void k_repack(
    const float* __restrict__ Ws, const float* __restrict__ Wx,
    const float* __restrict__ Wy, ushort_t* __restrict__ Wp){
  int e = blockIdx.x*256 + threadIdx.x;
  if (e >= 6*36*64*8) return;
  int j = e & 7; int lane = (e >> 3) & 63; int tt = e >> 9;
  int ks = tt % 36; int mtg = tt / 36;
  int co = mtg*32 + (lane & 31);
  int tap = ks >> 2;
  int ci = (ks & 3)*16 + ((lane >> 5) & 1)*8 + j;
  const float* src; int c;
  if (co < 64)      { src = Ws; c = co;       }
  else if (co < 128){ src = Wx; c = co - 64;  }
  else              { src = Wy; c = co - 128; }
  float w = src[(c*64 + ci)*9 + tap];
  ushort_t hi = f2bf(w);
  if (mtg < 2){
    Wp[e] = hi;
  } else {
    int eg = e - 2*18432;
    Wp[36864  + eg] = hi;
    Wp[110592 + eg] = f2bf(w - bf2f(hi));
  }
}

// ---------------------------------------------------------------------------
// Fused conv kernel: score (1x bf16) + gx/gy (3x split-bf16), staged directly
// from NCHW fp32 x. WG: 192 M-rows x 128 px (2 h-rows x 64 w).
// Emits score (bf16) and packed u16 fixed-point sample coords (u32/px).
// Grid 2048 XCD-swizzled: all WGs of batch b on XCD b&7.
// ---------------------------------------------------------------------------
__global__ __launch_bounds__(256, 2) void k_conv_all(
    const float* __restrict__ x, const ushort_t* __restrict__ Wp,
    const float* __restrict__ bs, const float* __restrict__ bx,
    const float* __restrict__ by,
    ushort_t* __restrict__ score, unsigned int* __restrict__ coords){
  int bid = blockIdx.x;
  int idx = bid >> 3;
  int b = (bid & 7) + 8*(idx >> 7);
  int rest = idx & 127;
  int h0 = (rest >> 1)*2;
  int wq = (rest & 1)*64;
  int t = threadIdx.x; int lane = t & 63; int wid = t >> 6;
  int n = lane & 31; int kh = lane >> 5;
  // XL: [4 rows][66 w1][64 ci] bf16, oct slot s = (ci>>3)^(w1&7); hi@0, lo@16896
  __shared__ __align__(16) ushort_t XL[2*16896];

  // zero the halo column not covered by data (w1=0 for wq=0, w1=65 for wq=64)
  if (t < 64){
    int r = t >> 4; int hilo = (t >> 3) & 1; int j = t & 7;
    int col = (wq == 0) ? 0 : 65;
    bf16x8 z = {0,0,0,0,0,0,0,0};
    *(bf16x8*)&XL[hilo*16896 + (r*66 + col)*64 + j*8] = z;
  }

  // stage: 4 rows (h0-1..h0+2) x 64 ci x full 128-w fp32 rows, keep window
  const float* xb = x + (size_t)b*64*HW_;
  #pragma unroll 4
  for (int i=0; i<32; i++){
    int c = i*256 + t;              // 0..8191
    int y_r = c >> 11;
    int rem = c & 2047;
    int ci = rem >> 5;
    int k  = rem & 31;
    int w0 = k*4;
    int y = h0 + y_r - 1;
    f32x4 v = {0.f,0.f,0.f,0.f};
    if (y >= 0 && y < 128)
      v = *(const f32x4*)(xb + ((size_t)(ci*128 + y))*128 + w0);
    if ((w0 + 3 >= wq - 1) && (w0 <= wq + 64)){
      #pragma unroll
      for (int j=0;j<4;j++){
        int w1 = w0 + j - wq + 1;
        if ((unsigned)w1 < 66u){
          float f = v[j];
          ushort_t hi = f2bf(f);
          ushort_t lo = f2bf(f - bf2f(hi));
          int addr = (y_r*66 + w1)*64 + (((ci>>3) ^ (w1&7))<<3) + (ci&7);
          XL[addr] = hi;
          XL[16896 + addr] = lo;
        }
      }
    }
  }
  __syncthreads();

  int hs = wid >> 1;             // output row within tile
  int wl = (wid & 1)*32 + n;     // w within 64-tile

  f32x16 acc0, acc1, acc2, acc3, acc4, acc5;
  #pragma unroll
  for (int reg=0; reg<16; reg++){
    int col = (reg & 3) + 8*(reg >> 2) + 4*kh;
    acc0[reg] = bs[col];    acc1[reg] = bs[32+col];
    acc2[reg] = bx[col];    acc3[reg] = bx[32+col];
    acc4[reg] = by[col];    acc5[reg] = by[32+col];
  }

  const ushort_t* aS = Wp + lane*8;
  const ushort_t* aG = Wp + 36864 + lane*8;
  #pragma unroll
  for (int tap=0; tap<9; tap++){
    int rb = tap/3; int dw = tap - rb*3 - 1;
    int row = rb + hs;
    int w1 = wl + dw + 1;
    #pragma unroll
    for (int q=0; q<4; q++){
      int ks = tap*4 + q;
      int off = (row*66 + w1)*64 + ((((q<<1)+kh) ^ (w1 & 7)) << 3);
      bf16x8 bh = *(const bf16x8*)&XL[off];
      bf16x8 bl = *(const bf16x8*)&XL[16896 + off];
      bf16x8 s0 = *(const bf16x8*)&aS[ks*512];
      bf16x8 s1 = *(const bf16x8*)&aS[(36+ks)*512];
      bf16x8 xh0 = *(const bf16x8*)&aG[ks*512];
      bf16x8 xh1 = *(const bf16x8*)&aG[(36+ks)*512];
      bf16x8 yh0 = *(const bf16x8*)&aG[(72+ks)*512];
      bf16x8 yh1 = *(const bf16x8*)&aG[(108+ks)*512];
      bf16x8 xl0 = *(const bf16x8*)&aG[(144+ks)*512];
      bf16x8 xl1 = *(const bf16x8*)&aG[(180+ks)*512];
      bf16x8 yl0 = *(const bf16x8*)&aG[(216+ks)*512];
      bf16x8 yl1 = *(const bf16x8*)&aG[(252+ks)*512];
      acc0 = MFMA(s0,  bh, acc0, 0,0,0);
      acc2 = MFMA(xh0, bh, acc2, 0,0,0);
      acc3 = MFMA(xh1, bh, acc3, 0,0,0);
      acc4 = MFMA(yh0, bh, acc4, 0,0,0);
      acc5 = MFMA(yh1, bh, acc5, 0,0,0);
      acc1 = MFMA(s1,  bh, acc1, 0,0,0);
      acc2 = MFMA(xl0, bh, acc2, 0,0,0);
      acc3 = MFMA(xl1, bh, acc3, 0,0,0);
      acc4 = MFMA(yl0, bh, acc4, 0,0,0);
      acc5 = MFMA(yl1, bh, acc5, 0,0,0);
      acc2 = MFMA(xh0, bl, acc2, 0,0,0);
      acc3 = MFMA(xh1, bl, acc3, 0,0,0);
      acc4 = MFMA(yh0, bl, acc4, 0,0,0);
      acc5 = MFMA(yh1, bl, acc5, 0,0,0);
    }
  }

  // epilogue: score bf16 + packed u16 coords (step 1/480 px, clamp [-2,129])
  int h = h0 + hs;
  ushort_t*     sb = score  + (size_t)b*64*HW_ + h*128 + wq + wl;
  unsigned int* cb = coords + (size_t)b*64*HW_ + h*128 + wq + wl;
  #pragma unroll
  for (int reg=0; reg<16; reg++){
    int col = (reg & 3) + 8*(reg >> 2) + 4*kh;
    sb[(size_t)col*HW_]      = f2bf(acc0[reg]);
    sb[(size_t)(32+col)*HW_] = f2bf(acc1[reg]);
    {
      float ix = fminf(fmaxf((acc2[reg]+1.f)*64.f - 0.5f, -2.f), 129.f);
      float iy = fminf(fmaxf((acc4[reg]+1.f)*64.f - 0.5f, -2.f), 129.f);
      unsigned ux = (unsigned)rintf((ix+2.f)*480.f);
      unsigned uy = (unsigned)rintf((iy+2.f)*480.f);
      cb[(size_t)col*HW_] = ux | (uy << 16);
    }
    {
      float ix = fminf(fmaxf((acc3[reg]+1.f)*64.f - 0.5f, -2.f), 129.f);
      float iy = fminf(fmaxf((acc5[reg]+1.f)*64.f - 0.5f, -2.f), 129.f);
      unsigned ux = (unsigned)rintf((ix+2.f)*480.f);
      unsigned uy = (unsigned)rintf((iy+2.f)*480.f);
      cb[(size_t)(32+col)*HW_] = ux | (uy << 16);
    }
  }
}

// ---------------------------------------------------------------------------
// Sampler: one WG per (b,co) channel; score plane in LDS; coords/out streamed.
// Grid 1024 XCD-swizzled to match conv's b -> XCD mapping (L2-hot reads).
// ---------------------------------------------------------------------------
__global__ __launch_bounds__(256, 4) void k_sample(
    const ushort_t* __restrict__ score, const unsigned int* __restrict__ coords,
    float* __restrict__ out){
  int bid = blockIdx.x;
  int idx = bid >> 3;
  int b  = (bid & 7) + 8*(idx >> 6);
  int co = idx & 63;
  int t = threadIdx.x;
  __shared__ __align__(16) ushort_t SC[128*136];   // stride 136 (16B-aligned rows)

  const ushort_t* sp = score + (size_t)(b*64 + co)*HW_;
  #pragma unroll
  for (int i=0;i<8;i++){
    int c = i*256 + t;                 // oct id 0..2047
    int y = c >> 4; int xg = (c & 15)*8;
    *(bf16x8*)&SC[y*136 + xg] = *(const bf16x8*)(sp + c*8);
  }
  __syncthreads();

  const unsigned int* cp = coords + (size_t)(b*64 + co)*HW_;
  float* op = out + (size_t)(b*64 + co)*HW_;
  #pragma unroll 1
  for (int k=0;k<8;k++){
    int px = (k*256 + t)*8;
    uint4v ca = *(const uint4v*)(cp + px);
    uint4v cb2 = *(const uint4v*)(cp + px + 4);
    float r[8];
    #pragma unroll
    for (int j=0;j<8;j++){
      unsigned u = (j < 4) ? ca[j] : cb2[j-4];
      float ix = (float)(u & 0xffffu)*(1.0f/480.0f) - 2.0f;
      float iy = (float)(u >> 16)   *(1.0f/480.0f) - 2.0f;
      float x0f = floorf(ix), y0f = floorf(iy);
      int x0 = (int)x0f, y0 = (int)y0f;
      float wx1 = ix - x0f, wy1 = iy - y0f;
      float wx0 = 1.f - wx1, wy0 = 1.f - wy1;
      int x0c = min(max(x0,0),127), x1c = min(max(x0+1,0),127);
      int y0c = min(max(y0,0),127), y1c = min(max(y0+1,0),127);
      bool vx0 = (unsigned)x0     < 128u, vx1 = (unsigned)(x0+1) < 128u;
      bool vy0 = (unsigned)y0     < 128u, vy1 = (unsigned)(y0+1) < 128u;
      float v00 = (vy0 && vx0) ? bf2f(SC[y0c*136 + x0c]) : 0.f;
      float v01 = (vy0 && vx1) ? bf2f(SC[y0c*136 + x1c]) : 0.f;
      float v10 = (vy1 && vx0) ? bf2f(SC[y1c*136 + x0c]) : 0.f;
      float v11 = (vy1 && vx1) ? bf2f(SC[y1c*136 + x1c]) : 0.f;
      r[j] = v00*(wy0*wx0) + v01*(wy0*wx1) + v10*(wy1*wx0) + v11*(wy1*wx1);
    }
    f32x4 r0 = {r[0],r[1],r[2],r[3]};
    f32x4 r1 = {r[4],r[5],r[6],r[7]};
    *(f32x4*)(op + px)     = r0;
    *(f32x4*)(op + px + 4) = r1;
  }
}

// ---------------------------------------------------------------------------
extern "C" void kernel_launch(void* const* d_in, const int* in_sizes, int n_in,
                              void* d_out, int out_size, void* d_ws, size_t ws_size,
                              hipStream_t stream){
  const float* x  = (const float*)d_in[0];
  const float* Ws = (const float*)d_in[1];
  const float* bs = (const float*)d_in[2];
  const float* Wx = (const float*)d_in[3];
  const float* bx = (const float*)d_in[4];
  const float* Wy = (const float*)d_in[5];
  const float* by = (const float*)d_in[6];
  float* out = (float*)d_out;
  ushort_t* ws  = (ushort_t*)d_ws;
  ushort_t*     score  = ws;                                   // 33.5 MB bf16
  unsigned int* coords = (unsigned int*)(ws + 16777216);       // 67.1 MB u32
  ushort_t*     Wp     = ws + 16777216 + 2*16777216;           // 0.37 MB

  k_repack  <<<dim3(432),  256, 0, stream>>>(Ws, Wx, Wy, Wp);
  k_conv_all<<<dim3(2048), 256, 0, stream>>>(x, Wp, bs, bx, by, score, coords);
  k_sample  <<<dim3(1024), 256, 0, stream>>>(score, coords, out);
}

// Round 6
// 287.334 us; speedup vs baseline: 1.2613x; 1.2613x over previous
//
#include <hip/hip_runtime.h>
#include <stdint.h>

typedef unsigned short ushort_t;
typedef short bf16x8 __attribute__((ext_vector_type(8)));
typedef float f32x4 __attribute__((ext_vector_type(4)));
typedef float f32x16 __attribute__((ext_vector_type(16)));
typedef unsigned int uint4v __attribute__((ext_vector_type(4)));

#define HW_ 16384

__device__ __forceinline__ float bf2f(ushort_t u){
  return __uint_as_float(((unsigned)u) << 16);
}
__device__ __forceinline__ ushort_t f2bf(float f){
  unsigned u = __float_as_uint(f);
  u += 0x7fffu + ((u >> 16) & 1u);
  return (ushort_t)(u >> 16);
}
#define MFMA __builtin_amdgcn_mfma_f32_32x32x16_bf16

// ---------------------------------------------------------------------------
// Wp layout (ushort elements):
//   [0      .. 36864)  : score hi A-frags,  mtg 0..1 = Ws rows 0..63
//   [36864  .. 110592) : gxy  hi A-frags,   mtg 0..3 = Wx0,Wx1,Wy0,Wy1
//   [110592 .. 184320) : gxy  lo A-frags,   same order
// Within a group: [mtg][ks 0..35][lane 0..63][j 0..7];
// co' = mtg*32 + (lane&31); tap = ks>>2; ci = (ks&3)*16 + (lane>>5)*8 + j.
// ---------------------------------------------------------------------------
__global__ __launch_bounds__(256) void k_repack(
    const float* __restrict__ Ws, const float* __restrict__ Wx,
    const float* __restrict__ Wy, ushort_t* __restrict__ Wp){
  int e = blockIdx.x*256 + threadIdx.x;
  if (e >= 6*36*64*8) return;
  int j = e & 7; int lane = (e >> 3) & 63; int tt = e >> 9;
  int ks = tt % 36; int mtg = tt / 36;
  int co = mtg*32 + (lane & 31);
  int tap = ks >> 2;
  int ci = (ks & 3)*16 + ((lane >> 5) & 1)*8 + j;
  const float* src; int c;
  if (co < 64)      { src = Ws; c = co;       }
  else if (co < 128){ src = Wx; c = co - 64;  }
  else              { src = Wy; c = co - 128; }
  float w = src[(c*64 + ci)*9 + tap];
  ushort_t hi = f2bf(w);
  if (mtg < 2){
    Wp[e] = hi;
  } else {
    int eg = e - 2*18432;
    Wp[36864  + eg] = hi;
    Wp[110592 + eg] = f2bf(w - bf2f(hi));
  }
}

// ---------------------------------------------------------------------------
// Fused conv kernel: score + gx/gy (split-bf16), staged directly from NCHW
// fp32 x via register-transposed coalesced loads (no scalar LDS traffic).
// WG tile: 192 M-rows x (2 h-rows x 64 w). Wave (mh, ph): M=96, N=64.
// Grid 2048 XCD-swizzled: all WGs of batch b on XCD b&7.
// ---------------------------------------------------------------------------
__global__ __launch_bounds__(256, 2) void k_conv_all(
    const float* __restrict__ x, const ushort_t* __restrict__ Wp,
    const float* __restrict__ bs, const float* __restrict__ bx,
    const float* __restrict__ by,
    ushort_t* __restrict__ score, unsigned int* __restrict__ coords){
  int bid = blockIdx.x;
  int idx = bid >> 3;
  int b = (bid & 7) + 8*(idx >> 7);
  int rest = idx & 127;
  int h0 = (rest >> 1)*2;
  int wq = (rest & 1)*64;
  int t = threadIdx.x; int lane = t & 63; int wid = t >> 6;
  int n = lane & 31; int kh = lane >> 5;
  // XL: [4 rows][66 w1][64 ci] bf16, oct slot s = (ci>>3)^(w1&7); hi@0, lo@16896
  __shared__ __align__(16) ushort_t XL[2*16896];

  // ---- staging: register-direct transpose, 2112 fragments of 8 ci ----
  const float* xb = x + (size_t)b*64*HW_;
  #pragma unroll 3
  for (int it=0; it<9; it++){
    int f = it*256 + t;
    if (f < 2112){
      int r   = f / 528;            // 0..3 (y row)
      int rem = f - r*528;
      int o   = rem / 66;           // 0..7 (ci oct)
      int w1  = rem - o*66;         // 0..65
      int y = h0 + r - 1;
      int w = wq + w1 - 1;
      bf16x8 hv = {0,0,0,0,0,0,0,0}, lv = {0,0,0,0,0,0,0,0};
      if (((unsigned)y < 128u) & ((unsigned)w < 128u)){
        const float* p = xb + (size_t)(o*8)*HW_ + y*128 + w;
        #pragma unroll
        for (int j=0;j<8;j++){
          float fv = p[(size_t)j*HW_];
          ushort_t hi = f2bf(fv);
          hv[j] = (short)hi;
          lv[j] = (short)f2bf(fv - bf2f(hi));
        }
      }
      int addr = (r*66 + w1)*64 + ((o ^ (w1 & 7))<<3);
      *(bf16x8*)&XL[addr]         = hv;
      *(bf16x8*)&XL[16896 + addr] = lv;
    }
  }
  __syncthreads();

  int mh = wid & 1;      // M half: channels mh*32..mh*32+31 of each conv
  int ph = wid >> 1;     // output h row within tile

  f32x16 acc_s[2], acc_x[2], acc_y[2];
  #pragma unroll
  for (int reg=0; reg<16; reg++){
    int col = mh*32 + (reg & 3) + 8*(reg >> 2) + 4*kh;
    float vs = bs[col], vx = bx[col], vy = by[col];
    #pragma unroll
    for (int ni=0; ni<2; ni++){
      acc_s[ni][reg] = vs; acc_x[ni][reg] = vx; acc_y[ni][reg] = vy;
    }
  }

  const ushort_t* aSb = Wp + mh*36*512 + lane*8;
  const ushort_t* aXh = Wp + 36864 + mh*36*512 + lane*8;
  const ushort_t* aYh = Wp + 36864 + (2+mh)*36*512 + lane*8;
  #pragma unroll
  for (int tap=0; tap<9; tap++){
    int rb = tap/3; int dw = tap - rb*3 - 1;
    int row = rb + ph;
    #pragma unroll
    for (int q=0; q<4; q++){
      int ks = tap*4 + q;
      bf16x8 s8 = *(const bf16x8*)&aSb[ks*512];
      bf16x8 xh = *(const bf16x8*)&aXh[ks*512];
      bf16x8 xl = *(const bf16x8*)&aXh[73728 + ks*512];
      bf16x8 yh = *(const bf16x8*)&aYh[ks*512];
      bf16x8 yl = *(const bf16x8*)&aYh[73728 + ks*512];
      #pragma unroll
      for (int ni=0; ni<2; ni++){
        int w1 = ni*32 + n + dw + 1;
        int off = (row*66 + w1)*64 + ((((q<<1)+kh) ^ (w1 & 7)) << 3);
        bf16x8 bh = *(const bf16x8*)&XL[off];
        bf16x8 bl = *(const bf16x8*)&XL[16896 + off];
        acc_s[ni] = MFMA(s8, bh, acc_s[ni], 0,0,0);
        acc_x[ni] = MFMA(xh, bh, acc_x[ni], 0,0,0);
        acc_y[ni] = MFMA(yh, bh, acc_y[ni], 0,0,0);
        acc_x[ni] = MFMA(xl, bh, acc_x[ni], 0,0,0);
        acc_y[ni] = MFMA(yl, bh, acc_y[ni], 0,0,0);
        acc_x[ni] = MFMA(xh, bl, acc_x[ni], 0,0,0);
        acc_y[ni] = MFMA(yh, bl, acc_y[ni], 0,0,0);
      }
    }
  }

  // epilogue: score bf16 + packed u16 coords (step 1/480 px, clamp [-2,129])
  int h = h0 + ph;
  #pragma unroll
  for (int ni=0; ni<2; ni++){
    int w = wq + ni*32 + n;
    ushort_t*     sb = score  + (size_t)b*64*HW_ + h*128 + w;
    unsigned int* cb = coords + (size_t)b*64*HW_ + h*128 + w;
    #pragma unroll
    for (int reg=0; reg<16; reg++){
      int col = mh*32 + (reg & 3) + 8*(reg >> 2) + 4*kh;
      sb[(size_t)col*HW_] = f2bf(acc_s[ni][reg]);
      float ix = fminf(fmaxf((acc_x[ni][reg]+1.f)*64.f - 0.5f, -2.f), 129.f);
      float iy = fminf(fmaxf((acc_y[ni][reg]+1.f)*64.f - 0.5f, -2.f), 129.f);
      unsigned ux = (unsigned)rintf((ix+2.f)*480.f);
      unsigned uy = (unsigned)rintf((iy+2.f)*480.f);
      cb[(size_t)col*HW_] = ux | (uy << 16);
    }
  }
}

// ---------------------------------------------------------------------------
// Sampler: one WG per (b,co) channel; score plane in LDS; coords/out streamed
// with a one-iteration coordinate prefetch pipeline.
// Grid 1024 XCD-swizzled to match conv's b -> XCD mapping (L2-hot reads).
// ---------------------------------------------------------------------------
__global__ __launch_bounds__(256, 4) void k_sample(
    const ushort_t* __restrict__ score, const unsigned int* __restrict__ coords,
    float* __restrict__ out){
  int bid = blockIdx.x;
  int idx = bid >> 3;
  int b  = (bid & 7) + 8*(idx >> 6);
  int co = idx & 63;
  int t = threadIdx.x;
  __shared__ __align__(16) ushort_t SC[128*136];   // stride 136 (16B-aligned rows)

  const ushort_t* sp = score + (size_t)(b*64 + co)*HW_;
  #pragma unroll
  for (int i=0;i<8;i++){
    int c = i*256 + t;                 // oct id 0..2047
    int y = c >> 4; int xg = (c & 15)*8;
    *(bf16x8*)&SC[y*136 + xg] = *(const bf16x8*)(sp + c*8);
  }
  __syncthreads();

  const unsigned int* cp = coords + (size_t)(b*64 + co)*HW_;
  float* op = out + (size_t)(b*64 + co)*HW_;
  uint4v ca = *(const uint4v*)(cp + t*8);
  uint4v cb2 = *(const uint4v*)(cp + t*8 + 4);
  #pragma unroll 1
  for (int k=0;k<8;k++){
    int px = (k*256 + t)*8;
    uint4v na, nb;
    if (k < 7){
      na = *(const uint4v*)(cp + px + 2048);
      nb = *(const uint4v*)(cp + px + 2052);
    }
    float r[8];
    #pragma unroll
    for (int j=0;j<8;j++){
      unsigned u = (j < 4) ? ca[j] : cb2[j-4];
      float ix = (float)(u & 0xffffu)*(1.0f/480.0f) - 2.0f;
      float iy = (float)(u >> 16)   *(1.0f/480.0f) - 2.0f;
      float x0f = floorf(ix), y0f = floorf(iy);
      int x0 = (int)x0f, y0 = (int)y0f;
      float wx1 = ix - x0f, wy1 = iy - y0f;
      float wx0 = 1.f - wx1, wy0 = 1.f - wy1;
      int x0c = min(max(x0,0),127), x1c = min(max(x0+1,0),127);
      int y0c = min(max(y0,0),127), y1c = min(max(y0+1,0),127);
      bool vx0 = (unsigned)x0     < 128u, vx1 = (unsigned)(x0+1) < 128u;
      bool vy0 = (unsigned)y0     < 128u, vy1 = (unsigned)(y0+1) < 128u;
      float v00 = (vy0 && vx0) ? bf2f(SC[y0c*136 + x0c]) : 0.f;
      float v01 = (vy0 && vx1) ? bf2f(SC[y0c*136 + x1c]) : 0.f;
      float v10 = (vy1 && vx0) ? bf2f(SC[y1c*136 + x0c]) : 0.f;
      float v11 = (vy1 && vx1) ? bf2f(SC[y1c*136 + x1c]) : 0.f;
      r[j] = v00*(wy0*wx0) + v01*(wy0*wx1) + v10*(wy1*wx0) + v11*(wy1*wx1);
    }
    f32x4 r0 = {r[0],r[1],r[2],r[3]};
    f32x4 r1 = {r[4],r[5],r[6],r[7]};
    *(f32x4*)(op + px)     = r0;
    *(f32x4*)(op + px + 4) = r1;
    ca = na; cb2 = nb;
  }
}

// ---------------------------------------------------------------------------
extern "C" void kernel_launch(void* const* d_in, const int* in_sizes, int n_in,
                              void* d_out, int out_size, void* d_ws, size_t ws_size,
                              hipStream_t stream){
  const float* x  = (const float*)d_in[0];
  const float* Ws = (const float*)d_in[1];
  const float* bs = (const float*)d_in[2];
  const float* Wx = (const float*)d_in[3];
  const float* bx = (const float*)d_in[4];
  const float* Wy = (const float*)d_in[5];
  const float* by = (const float*)d_in[6];
  float* out = (float*)d_out;
  ushort_t* ws  = (ushort_t*)d_ws;
  ushort_t*     score  = ws;                                   // 33.5 MB bf16
  unsigned int* coords = (unsigned int*)(ws + 16777216);       // 67.1 MB u32
  ushort_t*     Wp     = ws + 16777216 + 2*16777216;           // 0.37 MB

  k_repack  <<<dim3(432),  256, 0, stream>>>(Ws, Wx, Wy, Wp);
  k_conv_all<<<dim3(2048), 256, 0, stream>>>(x, Wp, bs, bx, by, score, coords);
  k_sample  <<<dim3(1024), 256, 0, stream>>>(score, coords, out);
}